// Round 4
// baseline (299.593 us; speedup 1.0000x reference)
//
#include <hip/hip_runtime.h>
#include <stdint.h>

#define AS1 __attribute__((address_space(1)))
#define AS3 __attribute__((address_space(3)))

typedef __attribute__((ext_vector_type(8))) short bf16x8;  // 8 x bf16 (4 VGPRs)
typedef __attribute__((ext_vector_type(4))) float f32x4;   // MFMA 16x16 C/D

__device__ __forceinline__ unsigned short f32_bf16(float f) {
  unsigned u = __float_as_uint(f);
  u += 0x7FFFu + ((u >> 16) & 1u);          // round-to-nearest-even
  return (unsigned short)(u >> 16);
}

__device__ __forceinline__ void async_ld16(const unsigned short* g, unsigned short* l) {
  // global -> LDS direct, 16B per lane; LDS dest must be base + lane*16 contiguous
  __builtin_amdgcn_global_load_lds((const AS1 void*)g, (AS3 void*)l, 16, 0, 0);
}

// ---------------- prep kernels ----------------
__global__ __launch_bounds__(256) void cvt_f32_bf16(const float* __restrict__ src,
                                                    unsigned short* __restrict__ dst, int n4) {
  int i = blockIdx.x * 256 + threadIdx.x;
  if (i >= n4) return;
  float4 v = ((const float4*)src)[i];
  ushort4 o;
  o.x = f32_bf16(v.x); o.y = f32_bf16(v.y); o.z = f32_bf16(v.z); o.w = f32_bf16(v.w);
  ((ushort4*)dst)[i] = o;
}

// src [K][N] f32 -> dst [N][K] bf16 ; grid (N/64, K/64), 256 threads
__global__ __launch_bounds__(256) void transpose_f32_bf16(const float* __restrict__ src,
                                                          unsigned short* __restrict__ dst,
                                                          int K, int N) {
  __shared__ unsigned short tile[64][65];   // +1 pad breaks bank conflicts
  int nt = blockIdx.x, kt = blockIdx.y, t = threadIdx.x;
  #pragma unroll
  for (int i = 0; i < 16; ++i) {
    int idx = t + i * 256;
    int r = idx >> 6, c = idx & 63;
    tile[r][c] = f32_bf16(src[(size_t)(kt * 64 + r) * N + nt * 64 + c]);
  }
  __syncthreads();
  #pragma unroll
  for (int i = 0; i < 16; ++i) {
    int idx = t + i * 256;
    int r = idx >> 6, c = idx & 63;
    dst[(size_t)(nt * 64 + r) * K + kt * 64 + c] = tile[c][r];
  }
}

// ------------- 128x128 bf16 MFMA GEMM core (m97 structure) -------------
template <int KDIM>
__device__ __forceinline__ void gemm_core(const unsigned short* __restrict__ A,
                                          const unsigned short* __restrict__ Bt,
                                          unsigned short* Als, unsigned short* Bls,
                                          int bm, int bn, f32x4 (&acc)[4][4]) {
  const int tid = threadIdx.x;
  const int w = tid >> 6, lane = tid & 63, quad = lane >> 4, l15 = lane & 15;
  const int wr = w >> 1, wc = w & 1;
  const int srow = lane >> 2, scol = (lane & 3) * 8;   // staging: 4 lanes per 32-wide row
  const unsigned short* Arow0 = A + (size_t)(bm * 128) * KDIM;
  const unsigned short* Brow0 = Bt + (size_t)(bn * 128) * KDIM;
  for (int k0 = 0; k0 < KDIM; k0 += 32) {
    __syncthreads();
    #pragma unroll
    for (int i = 0; i < 2; ++i) {
      int row = i * 64 + w * 16 + srow;
      async_ld16(Arow0 + (size_t)row * KDIM + k0 + scol, Als + i * 2048 + w * 512 + lane * 8);
      async_ld16(Brow0 + (size_t)row * KDIM + k0 + scol, Bls + i * 2048 + w * 512 + lane * 8);
    }
    __syncthreads();   // compiler drains vmcnt before s_barrier
    bf16x8 a[4], b[4];
    #pragma unroll
    for (int mi = 0; mi < 4; ++mi)
      a[mi] = *(const bf16x8*)(Als + (wr * 64 + mi * 16 + l15) * 32 + quad * 8);
    #pragma unroll
    for (int ni = 0; ni < 4; ++ni)
      b[ni] = *(const bf16x8*)(Bls + (wc * 64 + ni * 16 + l15) * 32 + quad * 8);
    #pragma unroll
    for (int mi = 0; mi < 4; ++mi)
      #pragma unroll
      for (int ni = 0; ni < 4; ++ni)
        acc[mi][ni] = __builtin_amdgcn_mfma_f32_16x16x32_bf16(a[mi], b[ni], acc[mi][ni], 0, 0, 0);
  }
}

// ------------- QKV GEMM + bias + RoPE epilogue (coalesced via per-wave LDS) -------------
// (256,2): allocator caps at 256 VGPR; default inference spilled acc[4][4] (R2: 1.5GB scratch WB).
__global__ __launch_bounds__(256, 2) void qkv_gemm(const unsigned short* __restrict__ Xb,
                                                   const unsigned short* __restrict__ WqkvT,
                                                   const float* __restrict__ qbias,
                                                   const float* __restrict__ vbias,
                                                   unsigned short* __restrict__ Qg,
                                                   unsigned short* __restrict__ Kg,
                                                   unsigned short* __restrict__ Vtg) {
  __shared__ unsigned short Als[128 * 32];
  __shared__ unsigned short Bls[128 * 32];
  __shared__ unsigned short Slds[4][64 * 72];   // per-wave epilogue staging (9216 B/wave)
  f32x4 acc[4][4] = {};
  const int bn = blockIdx.x, bm = blockIdx.y;
  gemm_core<1024>(Xb, WqkvT, Als, Bls, bm, bn, acc);

  const int tid = threadIdx.x;
  const int w = tid >> 6, lane = tid & 63, quad = lane >> 4, l15 = lane & 15;
  const int wr = w >> 1, wc = w & 1;
  const int part = bn >> 3;            // 0=q, 1=k, 2=v  (8 n-blocks per part)
  const int cb = (bn & 7) * 128 + wc * 64;     // wave channel base (one full head)
  const int h = cb >> 6;
  const int m0 = bm * 128 + wr * 64;           // wave row base (64 consecutive s)
  const int bb = m0 >> 11, s0 = m0 & 2047;
  unsigned short* Sw = Slds[w];

  if (part < 2) {
    // ---- Q/K: bias + RoPE (+ Q pre-scaled by 1/8: exact bf16 exponent shift;
    //      saves 64 VALU mul/iter in attention), stage [s][d] pad 72, 16B stores ----
    const float qscale = (part == 0) ? 0.125f : 1.f;
    #pragma unroll
    for (int ni = 0; ni < 4; ++ni) {
      int dd = ni * 16 + l15;                  // 0..63 within head
      float bias = (part == 0) ? qbias[cb + dd] : 0.f;
      float invf = exp2f((float)(dd >> 1) * (-13.287712379549449f / 32.f)); // 1e4^(-p/32)
      float sgn = (dd & 1) ? 1.f : -1.f;
      #pragma unroll
      for (int mi = 0; mi < 4; ++mi) {
        #pragma unroll
        for (int r = 0; r < 4; ++r) {
          int sl = mi * 16 + quad * 4 + r;     // s_local 0..63
          float val = acc[mi][ni][r] + bias;
          float partner = __shfl_xor(val, 1);  // rotary pair lives in lane^1
          float ang = (float)(s0 + sl) * invf;
          float sn, cs;
          __sincosf(ang, &sn, &cs);            // fast path: no Payne-Hanek, no scratch
          val = (val * cs + sgn * partner * sn) * qscale;
          Sw[sl * 72 + dd] = f32_bf16(val);
        }
      }
    }
    unsigned short* dstp = (part == 0) ? Qg : Kg;
    const size_t base = ((size_t)(bb * 16 + h) * 2048 + s0) * 64;  // contiguous 8KB region
    #pragma unroll
    for (int it = 0; it < 8; ++it) {
      int row = it * 8 + (lane >> 3), off = (lane & 7) * 8;
      bf16x8 v = *(const bf16x8*)(Sw + row * 72 + off);
      *(bf16x8*)(dstp + base + (size_t)row * 64 + off) = v;
    }
  } else {
    // ---- V: bias, stage tile [s][d] pad 68, write V^T rows (128B contiguous each) ----
    #pragma unroll
    for (int ni = 0; ni < 4; ++ni) {
      int dd = ni * 16 + l15;
      float bias = vbias[cb + dd];
      #pragma unroll
      for (int mi = 0; mi < 4; ++mi)
        #pragma unroll
        for (int r = 0; r < 4; ++r) {
          int sl = mi * 16 + quad * 4 + r;
          Sw[sl * 68 + dd] = f32_bf16(acc[mi][ni][r] + bias);
        }
    }
    const size_t vbase = (size_t)(bb * 16 + h) * 64 * 2048 + s0;
    #pragma unroll 4
    for (int dd = 0; dd < 64; ++dd) {
      unsigned short v = Sw[lane * 68 + dd];   // column read (tile transpose)
      Vtg[vbase + (size_t)dd * 2048 + lane] = v;  // 64 lanes x 2B = 128B contiguous
    }
  }
}

// ------------- causal flash attention -------------
// grid (qt=16, h=16, b=2), 256 threads; each wave owns 32 q-rows.
// LDS layout rule (R3 fix): all MFMA-fragment buffers use 32-short (64B) rows — the m97
// gemm-core pattern — R3's 128/256B rows put all 16 l15 lanes on one bank (16-way).
// K split by ki-chunk [2][128][32]; V split by k4-chunk [4][64][32]; P per-wave
// [2][32][32] (half-resident, quad-XOR chunk swizzle). LDS 48KB -> 3 blocks/CU.
__global__ __launch_bounds__(256, 3) void attn_fwd(const unsigned short* __restrict__ Qg,
                                                   const unsigned short* __restrict__ Kg,
                                                   const unsigned short* __restrict__ Vtg,
                                                   unsigned short* __restrict__ Og) {
  __shared__ unsigned short Kls[2 * 128 * 32];   // 16KB
  __shared__ unsigned short Vls[4 * 64 * 32];    // 16KB
  __shared__ unsigned short Pls[4][2 * 32 * 32]; // 16KB, per-wave
  // qt reversed on b=0 so co-resident block pairs (n, n+256) sum to uniform work
  const int qt = blockIdx.z ? blockIdx.x : (15 - blockIdx.x);
  const int h = blockIdx.y, b = blockIdx.z;
  const int bh = b * 16 + h;
  const int tid = threadIdx.x;
  const int w = tid >> 6, lane = tid & 63, quad = lane >> 4, l15 = lane & 15;
  const unsigned short* Qb = Qg + (size_t)bh * 2048 * 64;
  const unsigned short* Kb = Kg + (size_t)bh * 2048 * 64;
  const unsigned short* Vb = Vtg + (size_t)bh * 64 * 2048;
  const int q0 = qt * 128 + w * 32;

  bf16x8 aq[2][2];   // Q fragments (pre-scaled by 1/8) stay in registers
  #pragma unroll
  for (int mi = 0; mi < 2; ++mi)
    #pragma unroll
    for (int ki = 0; ki < 2; ++ki)
      aq[mi][ki] = *(const bf16x8*)(Qb + (size_t)(q0 + mi * 16 + l15) * 64 + ki * 32 + quad * 8);

  f32x4 o[2][4] = {};
  float m_st[2][4], l_st[2][4];
  #pragma unroll
  for (int mi = 0; mi < 2; ++mi)
    #pragma unroll
    for (int r = 0; r < 4; ++r) { m_st[mi][r] = -1e30f; l_st[mi][r] = 0.f; }

  unsigned short* Pw = Pls[w];

  for (int kt = 0; kt <= qt; ++kt) {
    __syncthreads();
    #pragma unroll
    for (int i = 0; i < 4; ++i) {
      int j = i * 4 + w;
      // K: buffer ki=j>>3, rows (j&7)*16+(lane>>2), 4 lanes per 64B row-chunk
      int kr = (j & 7) * 16 + (lane >> 2);
      int kc = (j >> 3) * 32 + (lane & 3) * 8;
      async_ld16(Kb + (size_t)(kt * 128 + kr) * 64 + kc, Kls + j * 512 + lane * 8);
      // V: buffer k4=j>>2, rows d=(j&3)*16+(lane>>2)
      int dd = (j & 3) * 16 + (lane >> 2);
      int vc = (j >> 2) * 32 + (lane & 3) * 8;
      async_ld16(Vb + (size_t)dd * 2048 + kt * 128 + vc, Vls + j * 512 + lane * 8);
    }
    __syncthreads();

    // S = Q K^T (per wave: 32 q-rows x 128 keys); Q carries the 1/8 scale
    f32x4 sc[2][8] = {};
    #pragma unroll
    for (int ki = 0; ki < 2; ++ki) {
      bf16x8 bk[8];
      #pragma unroll
      for (int ni = 0; ni < 8; ++ni)
        bk[ni] = *(const bf16x8*)(Kls + ki * 4096 + (ni * 16 + l15) * 32 + quad * 8);
      #pragma unroll
      for (int mi = 0; mi < 2; ++mi)
        #pragma unroll
        for (int ni = 0; ni < 8; ++ni)
          sc[mi][ni] = __builtin_amdgcn_mfma_f32_16x16x32_bf16(aq[mi][ki], bk[ni], sc[mi][ni], 0, 0, 0);
    }

    const bool diag = (kt == qt);
    float al[2][4];
    #pragma unroll
    for (int mi = 0; mi < 2; ++mi) {
      #pragma unroll
      for (int r = 0; r < 4; ++r) {
        int row = q0 + mi * 16 + quad * 4 + r;
        float mx = -1e30f;
        #pragma unroll
        for (int ni = 0; ni < 8; ++ni) {
          float v = sc[mi][ni][r];
          if (diag && (kt * 128 + ni * 16 + l15) > row) v = -1e9f; // causal mask
          sc[mi][ni][r] = v;
          mx = fmaxf(mx, v);
        }
        mx = fmaxf(mx, __shfl_xor(mx, 1));
        mx = fmaxf(mx, __shfl_xor(mx, 2));
        mx = fmaxf(mx, __shfl_xor(mx, 4));
        mx = fmaxf(mx, __shfl_xor(mx, 8));
        float mnew = fmaxf(m_st[mi][r], mx);
        float alpha = __expf(m_st[mi][r] - mnew);
        float sum = 0.f;
        #pragma unroll
        for (int ni = 0; ni < 8; ++ni) {
          float pv = __expf(sc[mi][ni][r] - mnew);
          sc[mi][ni][r] = pv;
          sum += pv;
        }
        sum += __shfl_xor(sum, 1);
        sum += __shfl_xor(sum, 2);
        sum += __shfl_xor(sum, 4);
        sum += __shfl_xor(sum, 8);
        l_st[mi][r] = l_st[mi][r] * alpha + sum;
        m_st[mi][r] = mnew;
        al[mi][r] = alpha;
      }
    }

    #pragma unroll
    for (int mi = 0; mi < 2; ++mi)
      #pragma unroll
      for (int di = 0; di < 4; ++di)
        #pragma unroll
        for (int r = 0; r < 4; ++r)
          o[mi][di][r] *= al[mi][r];

    // O += P V in two 64-key halves; P round-trips per-wave LDS (C->A layout).
    // Chunk swizzle: 16B chunk c of row stored at c ^ ((row>>2)&3) -> ~2-way.
    #pragma unroll
    for (int half = 0; half < 2; ++half) {
      #pragma unroll
      for (int nl = 0; nl < 4; ++nl) {
        int ck = ((nl & 1) << 1) | (l15 >> 3);
        int cs = ck ^ quad;                      // writer row quad = (row>>2)&3
        #pragma unroll
        for (int mi = 0; mi < 2; ++mi)
          #pragma unroll
          for (int r = 0; r < 4; ++r) {
            int rw = mi * 16 + quad * 4 + r;
            Pw[(nl >> 1) * 1024 + rw * 32 + cs * 8 + (l15 & 7)] =
                f32_bf16(sc[mi][half * 4 + nl][r]);
          }
      }
      // same-wave ds_write->ds_read: compiler orders via lgkmcnt, no barrier
      #pragma unroll
      for (int k4l = 0; k4l < 2; ++k4l) {
        int k4 = half * 2 + k4l;
        bf16x8 ap[2], bv[4];
        int csr = quad ^ ((l15 >> 2) & 3);       // reader row = mi*16+l15
        #pragma unroll
        for (int mi = 0; mi < 2; ++mi)
          ap[mi] = *(const bf16x8*)(Pw + k4l * 1024 + (mi * 16 + l15) * 32 + csr * 8);
        #pragma unroll
        for (int di = 0; di < 4; ++di)
          bv[di] = *(const bf16x8*)(Vls + k4 * 2048 + (di * 16 + l15) * 32 + quad * 8);
        #pragma unroll
        for (int mi = 0; mi < 2; ++mi)
          #pragma unroll
          for (int di = 0; di < 4; ++di)
            o[mi][di] = __builtin_amdgcn_mfma_f32_16x16x32_bf16(ap[mi], bv[di], o[mi][di], 0, 0, 0);
      }
    }
  }

  // epilogue: normalize, stage [32][64] in Pw with row-XOR chunk swizzle, 16B stores
  #pragma unroll
  for (int mi = 0; mi < 2; ++mi)
    #pragma unroll
    for (int r = 0; r < 4; ++r) {
      float inv = 1.f / l_st[mi][r];
      int sl = mi * 16 + quad * 4 + r;
      #pragma unroll
      for (int di = 0; di < 4; ++di) {
        int ck = di * 2 + (l15 >> 3);
        int cs = ck ^ (sl & 7);
        Pw[sl * 64 + cs * 8 + (l15 & 7)] = f32_bf16(o[mi][di][r] * inv);
      }
    }
  const size_t ob = ((size_t)(b * 2048 + q0)) * 1024 + h * 64;
  #pragma unroll
  for (int it = 0; it < 4; ++it) {
    int row = it * 8 + (lane >> 3);
    int cs = (lane & 7) ^ (row & 7);
    bf16x8 v = *(const bf16x8*)(Pw + row * 64 + cs * 8);
    *(bf16x8*)(Og + ob + (size_t)row * 1024 + (lane & 7) * 8) = v;
  }
}

// ------------- output projection -------------
__global__ __launch_bounds__(256, 2) void out_gemm(const unsigned short* __restrict__ Og,
                                                   const unsigned short* __restrict__ WoT,
                                                   float* __restrict__ Cout) {
  __shared__ unsigned short Als[128 * 32];
  __shared__ unsigned short Bls[128 * 32];
  f32x4 acc[4][4] = {};
  const int bn = blockIdx.x, bm = blockIdx.y;
  gemm_core<1024>(Og, WoT, Als, Bls, bm, bn, acc);
  const int tid = threadIdx.x;
  const int w = tid >> 6, lane = tid & 63, quad = lane >> 4, l15 = lane & 15;
  const int wr = w >> 1, wc = w & 1;
  #pragma unroll
  for (int mi = 0; mi < 4; ++mi)
    #pragma unroll
    for (int r = 0; r < 4; ++r) {
      int m = bm * 128 + wr * 64 + mi * 16 + quad * 4 + r;
      #pragma unroll
      for (int ni = 0; ni < 4; ++ni) {
        int n = bn * 128 + wc * 64 + ni * 16 + l15;
        Cout[(size_t)m * 1024 + n] = acc[mi][ni][r];  // 64B full line per quad
      }
    }
}

extern "C" void kernel_launch(void* const* d_in, const int* in_sizes, int n_in,
                              void* d_out, int out_size, void* d_ws, size_t ws_size,
                              hipStream_t stream) {
  const float* x      = (const float*)d_in[0];
  const float* w_qkv  = (const float*)d_in[1];
  const float* q_bias = (const float*)d_in[2];
  const float* v_bias = (const float*)d_in[3];
  const float* w_out  = (const float*)d_in[4];
  float* out = (float*)d_out;

  char* ws = (char*)d_ws;                       // 48 MB used
  unsigned short* Xb    = (unsigned short*)(ws);                  //  8 MB  x bf16 [4096][1024]
  unsigned short* WqkvT = (unsigned short*)(ws + (8u  << 20));    //  6 MB  w_qkv^T bf16 [3072][1024]
  unsigned short* WoT   = (unsigned short*)(ws + (14u << 20));    //  2 MB  w_out^T bf16 [1024][1024]
  unsigned short* Qg    = (unsigned short*)(ws + (16u << 20));    //  8 MB  Q [B,H,S,D] (x 1/8)
  unsigned short* Kg    = (unsigned short*)(ws + (24u << 20));    //  8 MB  K [B,H,S,D]
  unsigned short* Vtg   = (unsigned short*)(ws + (32u << 20));    //  8 MB  V^T [B,H,D,S]
  unsigned short* Og    = (unsigned short*)(ws + (40u << 20));    //  8 MB  attn out [B,S,C]

  cvt_f32_bf16<<<4096, 256, 0, stream>>>(x, Xb, (2 * 2048 * 1024) / 4);
  transpose_f32_bf16<<<dim3(48, 16), 256, 0, stream>>>(w_qkv, WqkvT, 1024, 3072);
  transpose_f32_bf16<<<dim3(16, 16), 256, 0, stream>>>(w_out, WoT, 1024, 1024);
  qkv_gemm<<<dim3(24, 32), 256, 0, stream>>>(Xb, WqkvT, q_bias, v_bias, Qg, Kg, Vtg);
  attn_fwd<<<dim3(16, 16, 2), 256, 0, stream>>>(Qg, Kg, Vtg, Og);
  out_gemm<<<dim3(8, 32), 256, 0, stream>>>(Og, WoT, out);
}

// Round 5
// 226.422 us; speedup vs baseline: 1.3232x; 1.3232x over previous
//
#include <hip/hip_runtime.h>
#include <stdint.h>

#define AS1 __attribute__((address_space(1)))
#define AS3 __attribute__((address_space(3)))

typedef __attribute__((ext_vector_type(8))) short bf16x8;  // 8 x bf16 (4 VGPRs)
typedef __attribute__((ext_vector_type(4))) float f32x4;   // MFMA 16x16 C/D

__device__ __forceinline__ unsigned short f32_bf16(float f) {
  unsigned u = __float_as_uint(f);
  u += 0x7FFFu + ((u >> 16) & 1u);          // round-to-nearest-even
  return (unsigned short)(u >> 16);
}

__device__ __forceinline__ void async_ld16(const unsigned short* g, unsigned short* l) {
  // global -> LDS direct, 16B per lane; LDS dest must be base + lane*16 contiguous
  __builtin_amdgcn_global_load_lds((const AS1 void*)g, (AS3 void*)l, 16, 0, 0);
}

// ---------------- prep kernels ----------------
__global__ __launch_bounds__(256) void cvt_f32_bf16(const float* __restrict__ src,
                                                    unsigned short* __restrict__ dst, int n4) {
  int i = blockIdx.x * 256 + threadIdx.x;
  if (i >= n4) return;
  float4 v = ((const float4*)src)[i];
  ushort4 o;
  o.x = f32_bf16(v.x); o.y = f32_bf16(v.y); o.z = f32_bf16(v.z); o.w = f32_bf16(v.w);
  ((ushort4*)dst)[i] = o;
}

// src [K][N] f32 -> dst [N][K] bf16 ; grid (N/64, K/64), 256 threads
__global__ __launch_bounds__(256) void transpose_f32_bf16(const float* __restrict__ src,
                                                          unsigned short* __restrict__ dst,
                                                          int K, int N) {
  __shared__ unsigned short tile[64][65];   // +1 pad breaks bank conflicts
  int nt = blockIdx.x, kt = blockIdx.y, t = threadIdx.x;
  #pragma unroll
  for (int i = 0; i < 16; ++i) {
    int idx = t + i * 256;
    int r = idx >> 6, c = idx & 63;
    tile[r][c] = f32_bf16(src[(size_t)(kt * 64 + r) * N + nt * 64 + c]);
  }
  __syncthreads();
  #pragma unroll
  for (int i = 0; i < 16; ++i) {
    int idx = t + i * 256;
    int r = idx >> 6, c = idx & 63;
    dst[(size_t)(nt * 64 + r) * K + kt * 64 + c] = tile[c][r];
  }
}

// ------------- 128x128 bf16 MFMA GEMM core (m97 structure) -------------
template <int KDIM>
__device__ __forceinline__ void gemm_core(const unsigned short* __restrict__ A,
                                          const unsigned short* __restrict__ Bt,
                                          unsigned short* Als, unsigned short* Bls,
                                          int bm, int bn, f32x4 (&acc)[4][4]) {
  const int tid = threadIdx.x;
  const int w = tid >> 6, lane = tid & 63, quad = lane >> 4, l15 = lane & 15;
  const int wr = w >> 1, wc = w & 1;
  const int srow = lane >> 2, scol = (lane & 3) * 8;   // staging: 4 lanes per 32-wide row
  const unsigned short* Arow0 = A + (size_t)(bm * 128) * KDIM;
  const unsigned short* Brow0 = Bt + (size_t)(bn * 128) * KDIM;
  for (int k0 = 0; k0 < KDIM; k0 += 32) {
    __syncthreads();
    #pragma unroll
    for (int i = 0; i < 2; ++i) {
      int row = i * 64 + w * 16 + srow;
      async_ld16(Arow0 + (size_t)row * KDIM + k0 + scol, Als + i * 2048 + w * 512 + lane * 8);
      async_ld16(Brow0 + (size_t)row * KDIM + k0 + scol, Bls + i * 2048 + w * 512 + lane * 8);
    }
    __syncthreads();   // compiler drains vmcnt before s_barrier
    bf16x8 a[4], b[4];
    #pragma unroll
    for (int mi = 0; mi < 4; ++mi)
      a[mi] = *(const bf16x8*)(Als + (wr * 64 + mi * 16 + l15) * 32 + quad * 8);
    #pragma unroll
    for (int ni = 0; ni < 4; ++ni)
      b[ni] = *(const bf16x8*)(Bls + (wc * 64 + ni * 16 + l15) * 32 + quad * 8);
    #pragma unroll
    for (int mi = 0; mi < 4; ++mi)
      #pragma unroll
      for (int ni = 0; ni < 4; ++ni)
        acc[mi][ni] = __builtin_amdgcn_mfma_f32_16x16x32_bf16(a[mi], b[ni], acc[mi][ni], 0, 0, 0);
  }
}

// ------------- QKV GEMM + bias + RoPE epilogue (coalesced via per-wave LDS) -------------
// (256,2): allocator caps at 256 VGPR; default inference spilled acc[4][4] (R2: 1.5GB scratch WB).
__global__ __launch_bounds__(256, 2) void qkv_gemm(const unsigned short* __restrict__ Xb,
                                                   const unsigned short* __restrict__ WqkvT,
                                                   const float* __restrict__ qbias,
                                                   const float* __restrict__ vbias,
                                                   unsigned short* __restrict__ Qg,
                                                   unsigned short* __restrict__ Kg,
                                                   unsigned short* __restrict__ Vtg) {
  __shared__ unsigned short Als[128 * 32];
  __shared__ unsigned short Bls[128 * 32];
  __shared__ unsigned short Slds[4][64 * 72];   // per-wave epilogue staging (9216 B/wave)
  f32x4 acc[4][4] = {};
  const int bn = blockIdx.x, bm = blockIdx.y;
  gemm_core<1024>(Xb, WqkvT, Als, Bls, bm, bn, acc);

  const int tid = threadIdx.x;
  const int w = tid >> 6, lane = tid & 63, quad = lane >> 4, l15 = lane & 15;
  const int wr = w >> 1, wc = w & 1;
  const int part = bn >> 3;            // 0=q, 1=k, 2=v  (8 n-blocks per part)
  const int cb = (bn & 7) * 128 + wc * 64;     // wave channel base (one full head)
  const int h = cb >> 6;
  const int m0 = bm * 128 + wr * 64;           // wave row base (64 consecutive s)
  const int bb = m0 >> 11, s0 = m0 & 2047;
  unsigned short* Sw = Slds[w];

  if (part < 2) {
    // ---- Q/K: bias + RoPE (+ Q pre-scaled by 1/8: exact bf16 exponent shift;
    //      saves 64 VALU mul/iter in attention), stage [s][d] pad 72, 16B stores ----
    const float qscale = (part == 0) ? 0.125f : 1.f;
    #pragma unroll
    for (int ni = 0; ni < 4; ++ni) {
      int dd = ni * 16 + l15;                  // 0..63 within head
      float bias = (part == 0) ? qbias[cb + dd] : 0.f;
      float invf = exp2f((float)(dd >> 1) * (-13.287712379549449f / 32.f)); // 1e4^(-p/32)
      float sgn = (dd & 1) ? 1.f : -1.f;
      #pragma unroll
      for (int mi = 0; mi < 4; ++mi) {
        #pragma unroll
        for (int r = 0; r < 4; ++r) {
          int sl = mi * 16 + quad * 4 + r;     // s_local 0..63
          float val = acc[mi][ni][r] + bias;
          float partner = __shfl_xor(val, 1);  // rotary pair lives in lane^1
          float ang = (float)(s0 + sl) * invf;
          float sn, cs;
          __sincosf(ang, &sn, &cs);            // fast path: no Payne-Hanek, no scratch
          val = (val * cs + sgn * partner * sn) * qscale;
          Sw[sl * 72 + dd] = f32_bf16(val);
        }
      }
    }
    unsigned short* dstp = (part == 0) ? Qg : Kg;
    const size_t base = ((size_t)(bb * 16 + h) * 2048 + s0) * 64;  // contiguous 8KB region
    #pragma unroll
    for (int it = 0; it < 8; ++it) {
      int row = it * 8 + (lane >> 3), off = (lane & 7) * 8;
      bf16x8 v = *(const bf16x8*)(Sw + row * 72 + off);
      *(bf16x8*)(dstp + base + (size_t)row * 64 + off) = v;
    }
  } else {
    // ---- V: bias, stage tile [s][d] pad 68, write V^T rows (128B contiguous each) ----
    #pragma unroll
    for (int ni = 0; ni < 4; ++ni) {
      int dd = ni * 16 + l15;
      float bias = vbias[cb + dd];
      #pragma unroll
      for (int mi = 0; mi < 4; ++mi)
        #pragma unroll
        for (int r = 0; r < 4; ++r) {
          int sl = mi * 16 + quad * 4 + r;
          Sw[sl * 68 + dd] = f32_bf16(acc[mi][ni][r] + bias);
        }
    }
    const size_t vbase = (size_t)(bb * 16 + h) * 64 * 2048 + s0;
    #pragma unroll 4
    for (int dd = 0; dd < 64; ++dd) {
      unsigned short v = Sw[lane * 68 + dd];   // column read (tile transpose)
      Vtg[vbase + (size_t)dd * 2048 + lane] = v;  // 64 lanes x 2B = 128B contiguous
    }
  }
}

// ------------- causal flash attention -------------
// grid (qt=16, h=16, b=2), 256 threads; each wave owns 32 q-rows.
// LDS layout (R4, keep): 32-short (64B) rows everywhere (m97 pattern); K [2][128][32],
// V [4][64][32], P per-wave [2][32][32] swizzled. Conflicts 1.73e7 -> 5e6 (verified R4).
// Launch bounds (R5 fix): (256,2) NOT (256,3) — the 3-wave cap squeezed VGPR to 84 and
// spilled sc[2][8] (R4: 111MB scratch WB + 113MB scratch reads). ~100 live floats need
// the 256-VGPR budget; LDS=48KB gives the 2 blocks/CU anyway.
__global__ __launch_bounds__(256, 2) void attn_fwd(const unsigned short* __restrict__ Qg,
                                                   const unsigned short* __restrict__ Kg,
                                                   const unsigned short* __restrict__ Vtg,
                                                   unsigned short* __restrict__ Og) {
  __shared__ unsigned short Kls[2 * 128 * 32];   // 16KB
  __shared__ unsigned short Vls[4 * 64 * 32];    // 16KB
  __shared__ unsigned short Pls[4][2 * 32 * 32]; // 16KB, per-wave
  // qt reversed on b=0 so co-resident block pairs (n, n+256) sum to uniform work
  const int qt = blockIdx.z ? blockIdx.x : (15 - blockIdx.x);
  const int h = blockIdx.y, b = blockIdx.z;
  const int bh = b * 16 + h;
  const int tid = threadIdx.x;
  const int w = tid >> 6, lane = tid & 63, quad = lane >> 4, l15 = lane & 15;
  const unsigned short* Qb = Qg + (size_t)bh * 2048 * 64;
  const unsigned short* Kb = Kg + (size_t)bh * 2048 * 64;
  const unsigned short* Vb = Vtg + (size_t)bh * 64 * 2048;
  const int q0 = qt * 128 + w * 32;

  bf16x8 aq[2][2];   // Q fragments (pre-scaled by 1/8) stay in registers
  #pragma unroll
  for (int mi = 0; mi < 2; ++mi)
    #pragma unroll
    for (int ki = 0; ki < 2; ++ki)
      aq[mi][ki] = *(const bf16x8*)(Qb + (size_t)(q0 + mi * 16 + l15) * 64 + ki * 32 + quad * 8);

  f32x4 o[2][4] = {};
  float m_st[2][4], l_st[2][4];
  #pragma unroll
  for (int mi = 0; mi < 2; ++mi)
    #pragma unroll
    for (int r = 0; r < 4; ++r) { m_st[mi][r] = -1e30f; l_st[mi][r] = 0.f; }

  unsigned short* Pw = Pls[w];

  for (int kt = 0; kt <= qt; ++kt) {
    __syncthreads();
    #pragma unroll
    for (int i = 0; i < 4; ++i) {
      int j = i * 4 + w;
      // K: buffer ki=j>>3, rows (j&7)*16+(lane>>2), 4 lanes per 64B row-chunk
      int kr = (j & 7) * 16 + (lane >> 2);
      int kc = (j >> 3) * 32 + (lane & 3) * 8;
      async_ld16(Kb + (size_t)(kt * 128 + kr) * 64 + kc, Kls + j * 512 + lane * 8);
      // V: buffer k4=j>>2, rows d=(j&3)*16+(lane>>2)
      int dd = (j & 3) * 16 + (lane >> 2);
      int vc = (j >> 2) * 32 + (lane & 3) * 8;
      async_ld16(Vb + (size_t)dd * 2048 + kt * 128 + vc, Vls + j * 512 + lane * 8);
    }
    __syncthreads();

    // S = Q K^T (per wave: 32 q-rows x 128 keys); Q carries the 1/8 scale
    f32x4 sc[2][8] = {};
    #pragma unroll
    for (int ki = 0; ki < 2; ++ki) {
      bf16x8 bk[8];
      #pragma unroll
      for (int ni = 0; ni < 8; ++ni)
        bk[ni] = *(const bf16x8*)(Kls + ki * 4096 + (ni * 16 + l15) * 32 + quad * 8);
      #pragma unroll
      for (int mi = 0; mi < 2; ++mi)
        #pragma unroll
        for (int ni = 0; ni < 8; ++ni)
          sc[mi][ni] = __builtin_amdgcn_mfma_f32_16x16x32_bf16(aq[mi][ki], bk[ni], sc[mi][ni], 0, 0, 0);
    }

    const bool diag = (kt == qt);
    float al[2][4];
    #pragma unroll
    for (int mi = 0; mi < 2; ++mi) {
      #pragma unroll
      for (int r = 0; r < 4; ++r) {
        int row = q0 + mi * 16 + quad * 4 + r;
        float mx = -1e30f;
        #pragma unroll
        for (int ni = 0; ni < 8; ++ni) {
          float v = sc[mi][ni][r];
          if (diag && (kt * 128 + ni * 16 + l15) > row) v = -1e9f; // causal mask
          sc[mi][ni][r] = v;
          mx = fmaxf(mx, v);
        }
        mx = fmaxf(mx, __shfl_xor(mx, 1));
        mx = fmaxf(mx, __shfl_xor(mx, 2));
        mx = fmaxf(mx, __shfl_xor(mx, 4));
        mx = fmaxf(mx, __shfl_xor(mx, 8));
        float mnew = fmaxf(m_st[mi][r], mx);
        float alpha = __expf(m_st[mi][r] - mnew);
        float sum = 0.f;
        #pragma unroll
        for (int ni = 0; ni < 8; ++ni) {
          float pv = __expf(sc[mi][ni][r] - mnew);
          sc[mi][ni][r] = pv;
          sum += pv;
        }
        sum += __shfl_xor(sum, 1);
        sum += __shfl_xor(sum, 2);
        sum += __shfl_xor(sum, 4);
        sum += __shfl_xor(sum, 8);
        l_st[mi][r] = l_st[mi][r] * alpha + sum;
        m_st[mi][r] = mnew;
        al[mi][r] = alpha;
      }
    }

    #pragma unroll
    for (int mi = 0; mi < 2; ++mi)
      #pragma unroll
      for (int di = 0; di < 4; ++di)
        #pragma unroll
        for (int r = 0; r < 4; ++r)
          o[mi][di][r] *= al[mi][r];

    // O += P V in two 64-key halves; P round-trips per-wave LDS (C->A layout).
    // Chunk swizzle: 16B chunk c of row stored at c ^ ((row>>2)&3) -> ~2-way.
    #pragma unroll
    for (int half = 0; half < 2; ++half) {
      #pragma unroll
      for (int nl = 0; nl < 4; ++nl) {
        int ck = ((nl & 1) << 1) | (l15 >> 3);
        int cs = ck ^ quad;                      // writer row quad = (row>>2)&3
        #pragma unroll
        for (int mi = 0; mi < 2; ++mi)
          #pragma unroll
          for (int r = 0; r < 4; ++r) {
            int rw = mi * 16 + quad * 4 + r;
            Pw[(nl >> 1) * 1024 + rw * 32 + cs * 8 + (l15 & 7)] =
                f32_bf16(sc[mi][half * 4 + nl][r]);
          }
      }
      // same-wave ds_write->ds_read: compiler orders via lgkmcnt, no barrier
      #pragma unroll
      for (int k4l = 0; k4l < 2; ++k4l) {
        int k4 = half * 2 + k4l;
        bf16x8 ap[2], bv[4];
        int csr = quad ^ ((l15 >> 2) & 3);       // reader row = mi*16+l15
        #pragma unroll
        for (int mi = 0; mi < 2; ++mi)
          ap[mi] = *(const bf16x8*)(Pw + k4l * 1024 + (mi * 16 + l15) * 32 + csr * 8);
        #pragma unroll
        for (int di = 0; di < 4; ++di)
          bv[di] = *(const bf16x8*)(Vls + k4 * 2048 + (di * 16 + l15) * 32 + quad * 8);
        #pragma unroll
        for (int mi = 0; mi < 2; ++mi)
          #pragma unroll
          for (int di = 0; di < 4; ++di)
            o[mi][di] = __builtin_amdgcn_mfma_f32_16x16x32_bf16(ap[mi], bv[di], o[mi][di], 0, 0, 0);
      }
    }
  }

  // epilogue: normalize, stage [32][64] in Pw with row-XOR chunk swizzle, 16B stores
  #pragma unroll
  for (int mi = 0; mi < 2; ++mi)
    #pragma unroll
    for (int r = 0; r < 4; ++r) {
      float inv = 1.f / l_st[mi][r];
      int sl = mi * 16 + quad * 4 + r;
      #pragma unroll
      for (int di = 0; di < 4; ++di) {
        int ck = di * 2 + (l15 >> 3);
        int cs = ck ^ (sl & 7);
        Pw[sl * 64 + cs * 8 + (l15 & 7)] = f32_bf16(o[mi][di][r] * inv);
      }
    }
  const size_t ob = ((size_t)(b * 2048 + q0)) * 1024 + h * 64;
  #pragma unroll
  for (int it = 0; it < 4; ++it) {
    int row = it * 8 + (lane >> 3);
    int cs = (lane & 7) ^ (row & 7);
    bf16x8 v = *(const bf16x8*)(Pw + row * 64 + cs * 8);
    *(bf16x8*)(Og + ob + (size_t)row * 1024 + (lane & 7) * 8) = v;
  }
}

// ------------- output projection -------------
__global__ __launch_bounds__(256, 2) void out_gemm(const unsigned short* __restrict__ Og,
                                                   const unsigned short* __restrict__ WoT,
                                                   float* __restrict__ Cout) {
  __shared__ unsigned short Als[128 * 32];
  __shared__ unsigned short Bls[128 * 32];
  f32x4 acc[4][4] = {};
  const int bn = blockIdx.x, bm = blockIdx.y;
  gemm_core<1024>(Og, WoT, Als, Bls, bm, bn, acc);
  const int tid = threadIdx.x;
  const int w = tid >> 6, lane = tid & 63, quad = lane >> 4, l15 = lane & 15;
  const int wr = w >> 1, wc = w & 1;
  #pragma unroll
  for (int mi = 0; mi < 4; ++mi)
    #pragma unroll
    for (int r = 0; r < 4; ++r) {
      int m = bm * 128 + wr * 64 + mi * 16 + quad * 4 + r;
      #pragma unroll
      for (int ni = 0; ni < 4; ++ni) {
        int n = bn * 128 + wc * 64 + ni * 16 + l15;
        Cout[(size_t)m * 1024 + n] = acc[mi][ni][r];  // 64B full line per quad
      }
    }
}

extern "C" void kernel_launch(void* const* d_in, const int* in_sizes, int n_in,
                              void* d_out, int out_size, void* d_ws, size_t ws_size,
                              hipStream_t stream) {
  const float* x      = (const float*)d_in[0];
  const float* w_qkv  = (const float*)d_in[1];
  const float* q_bias = (const float*)d_in[2];
  const float* v_bias = (const float*)d_in[3];
  const float* w_out  = (const float*)d_in[4];
  float* out = (float*)d_out;

  char* ws = (char*)d_ws;                       // 48 MB used
  unsigned short* Xb    = (unsigned short*)(ws);                  //  8 MB  x bf16 [4096][1024]
  unsigned short* WqkvT = (unsigned short*)(ws + (8u  << 20));    //  6 MB  w_qkv^T bf16 [3072][1024]
  unsigned short* WoT   = (unsigned short*)(ws + (14u << 20));    //  2 MB  w_out^T bf16 [1024][1024]
  unsigned short* Qg    = (unsigned short*)(ws + (16u << 20));    //  8 MB  Q [B,H,S,D] (x 1/8)
  unsigned short* Kg    = (unsigned short*)(ws + (24u << 20));    //  8 MB  K [B,H,S,D]
  unsigned short* Vtg   = (unsigned short*)(ws + (32u << 20));    //  8 MB  V^T [B,H,D,S]
  unsigned short* Og    = (unsigned short*)(ws + (40u << 20));    //  8 MB  attn out [B,S,C]

  cvt_f32_bf16<<<4096, 256, 0, stream>>>(x, Xb, (2 * 2048 * 1024) / 4);
  transpose_f32_bf16<<<dim3(48, 16), 256, 0, stream>>>(w_qkv, WqkvT, 1024, 3072);
  transpose_f32_bf16<<<dim3(16, 16), 256, 0, stream>>>(w_out, WoT, 1024, 1024);
  qkv_gemm<<<dim3(24, 32), 256, 0, stream>>>(Xb, WqkvT, q_bias, v_bias, Qg, Kg, Vtg);
  attn_fwd<<<dim3(16, 16, 2), 256, 0, stream>>>(Qg, Kg, Vtg, Og);
  out_gemm<<<dim3(8, 32), 256, 0, stream>>>(Og, WoT, out);
}